// Round 1
// baseline (373.515 us; speedup 1.0000x reference)
//
#include <hip/hip_runtime.h>
#include <math.h>

// Problem constants: B=4, L=32, HP=32, H=64, W=64, D=32, DFFN=64
// x: (4, 2048, 64, 64) fp32.  a = x[:, :1024], b = x[:, 1024:]
// out: mixed (4*1024*64*64 floats) + sigmoid(gate).mean() + mask.mean()

__device__ __forceinline__ float sigf(float v) { return 1.0f / (1.0f + __expf(-v)); }

// ---------------------------------------------------------------------------
// Kernel A: per-(b,l,hp) stats over 4096 elements of a and b, then in_proj.
// grid 4096 blocks, 256 threads. One full read of x (134 MB) -> HBM-bound.
// ---------------------------------------------------------------------------
__global__ __launch_bounds__(256) void k_stats(
    const float* __restrict__ x, const float* __restrict__ in_proj_w,
    const float* __restrict__ in_proj_b, const float* __restrict__ layer_emb,
    float* __restrict__ feat)
{
    __shared__ float red[4][9];
    __shared__ float tot[9];
    const int bid = blockIdx.x;
    const int hp = bid & 31, l = (bid >> 5) & 31, bb = bid >> 10;
    const float4* pa = (const float4*)(x + (size_t)(bb * 2048 + l * 32 + hp) * 4096);
    const float4* pb = (const float4*)(x + (size_t)(bb * 2048 + 1024 + l * 32 + hp) * 4096);
    const int t = threadIdx.x;

    float sa = 0.f, saa = 0.f, sb = 0.f, sbb = 0.f, sab = 0.f;
    float mna = 3.4e38f, mxa = -3.4e38f, mnb = 3.4e38f, mxb = -3.4e38f;
#pragma unroll
    for (int it = 0; it < 4; ++it) {
        float4 a4 = pa[t + it * 256];
        float4 b4 = pb[t + it * 256];
        sa  += a4.x + a4.y + a4.z + a4.w;
        sb  += b4.x + b4.y + b4.z + b4.w;
        saa += a4.x * a4.x + a4.y * a4.y + a4.z * a4.z + a4.w * a4.w;
        sbb += b4.x * b4.x + b4.y * b4.y + b4.z * b4.z + b4.w * b4.w;
        sab += a4.x * b4.x + a4.y * b4.y + a4.z * b4.z + a4.w * b4.w;
        mna = fminf(mna, fminf(fminf(a4.x, a4.y), fminf(a4.z, a4.w)));
        mxa = fmaxf(mxa, fmaxf(fmaxf(a4.x, a4.y), fmaxf(a4.z, a4.w)));
        mnb = fminf(mnb, fminf(fminf(b4.x, b4.y), fminf(b4.z, b4.w)));
        mxb = fmaxf(mxb, fmaxf(fmaxf(b4.x, b4.y), fmaxf(b4.z, b4.w)));
    }
#pragma unroll
    for (int m = 1; m < 64; m <<= 1) {
        sa  += __shfl_xor(sa, m);
        saa += __shfl_xor(saa, m);
        sb  += __shfl_xor(sb, m);
        sbb += __shfl_xor(sbb, m);
        sab += __shfl_xor(sab, m);
        mna = fminf(mna, __shfl_xor(mna, m));
        mxa = fmaxf(mxa, __shfl_xor(mxa, m));
        mnb = fminf(mnb, __shfl_xor(mnb, m));
        mxb = fmaxf(mxb, __shfl_xor(mxb, m));
    }
    const int lane = t & 63, wv = t >> 6;
    if (lane == 0) {
        red[wv][0] = sa;  red[wv][1] = saa; red[wv][2] = sb;  red[wv][3] = sbb;
        red[wv][4] = sab; red[wv][5] = mna; red[wv][6] = mxa; red[wv][7] = mnb;
        red[wv][8] = mxb;
    }
    __syncthreads();
    if (t == 0) {
#pragma unroll
        for (int q = 0; q < 5; ++q) tot[q] = red[0][q] + red[1][q] + red[2][q] + red[3][q];
        tot[5] = fminf(fminf(red[0][5], red[1][5]), fminf(red[2][5], red[3][5]));
        tot[6] = fmaxf(fmaxf(red[0][6], red[1][6]), fmaxf(red[2][6], red[3][6]));
        tot[7] = fminf(fminf(red[0][7], red[1][7]), fminf(red[2][7], red[3][7]));
        tot[8] = fmaxf(fmaxf(red[0][8], red[1][8]), fmaxf(red[2][8], red[3][8]));
    }
    __syncthreads();
    if (t < 32) {
        const float SA = tot[0], SAA = tot[1], SB = tot[2], SBB = tot[3], SAB = tot[4];
        const float inv_n = 1.f / 4096.f, inv_nm1 = 1.f / 4095.f;
        float st[12];
        st[0] = SA * inv_n;
        st[1] = sqrtf(fmaxf(SAA - SA * SA * inv_n, 0.f) * inv_nm1);
        st[2] = tot[5]; st[3] = tot[6];
        st[4] = SB * inv_n;
        st[5] = sqrtf(fmaxf(SBB - SB * SB * inv_n, 0.f) * inv_nm1);
        st[6] = tot[7]; st[7] = tot[8];
        const float SD = SA - SB, SDD = SAA - 2.f * SAB + SBB;
        st[8]  = SD * inv_n;
        st[9]  = sqrtf(fmaxf(SDD - SD * SD * inv_n, 0.f) * inv_nm1);
        st[10] = sqrtf(fmaxf(SDD, 0.f));
        const float na = fmaxf(sqrtf(SAA), 1e-8f), nb2 = fmaxf(sqrtf(SBB), 1e-8f);
        st[11] = SAB / (na * nb2);
        float acc = in_proj_b[t] + layer_emb[l * 32 + t];
#pragma unroll
        for (int s2 = 0; s2 < 12; ++s2) acc += st[s2] * in_proj_w[t * 12 + s2];
        // feat layout: [l][b][hp][d]
        feat[((l * 4 + bb) * 32 + hp) * 32 + t] = acc;
    }
}

// ---------------------------------------------------------------------------
// Kernel B: the RWKV scan. 128 blocks (one per (b,hp) sequence), 64 threads
// (single wave). d = lane&31; both 32-lane halves duplicate channel work
// except cm_k, which uses all 64 lanes. Weights in LDS, transposed + padded
// (stride 33 / 65) so the j-loop weight reads are bank-conflict-free.
// ---------------------------------------------------------------------------
__global__ __launch_bounds__(64) void k_scan(
    const float* __restrict__ feat,
    const float* __restrict__ time_decay, const float* __restrict__ time_first,
    const float* __restrict__ ln_tm_g, const float* __restrict__ ln_tm_b,
    const float* __restrict__ tm_r, const float* __restrict__ tm_k,
    const float* __restrict__ tm_v, const float* __restrict__ tm_out,
    const float* __restrict__ ln_cm_g, const float* __restrict__ ln_cm_b,
    const float* __restrict__ cm_k, const float* __restrict__ cm_v,
    const float* __restrict__ cm_r, float* __restrict__ feats_out)
{
    __shared__ float wT_r[32 * 33];   // [j][d] = tm_r[d][j]
    __shared__ float wT_k[32 * 33];
    __shared__ float wT_v[32 * 33];
    __shared__ float wT_o[32 * 33];
    __shared__ float wT_cr[32 * 33];
    __shared__ float wT_ck[32 * 65];  // [j][e] = cm_k[e][j], e<64
    __shared__ float wT_cv[64 * 33];  // [j][d] = cm_v[d][j], j<64
    __shared__ __align__(16) float xn_s[32];
    __shared__ __align__(16) float wkv_s[32];
    __shared__ __align__(16) float xn2_s[32];
    __shared__ __align__(16) float kk_s[64];

    const int t = threadIdx.x;
    const int d = t & 31;
    const int half = t >> 5;

    for (int i = t; i < 1024; i += 64) {
        const int row = i >> 5, col = i & 31;   // original [row][col]
        wT_r[col * 33 + row]  = tm_r[i];
        wT_k[col * 33 + row]  = tm_k[i];
        wT_v[col * 33 + row]  = tm_v[i];
        wT_o[col * 33 + row]  = tm_out[i];
        wT_cr[col * 33 + row] = cm_r[i];
    }
    for (int i = t; i < 2048; i += 64) {
        const int e = i >> 5, j = i & 31;       // cm_k[e][j], e<64
        wT_ck[j * 65 + e] = cm_k[i];
        const int r2 = i >> 6, c2 = i & 63;     // cm_v[r2][c2], r2<32
        wT_cv[c2 * 33 + r2] = cm_v[i];
    }
    const float gt = ln_tm_g[d], bt = ln_tm_b[d];
    const float gc = ln_cm_g[d], bc = ln_cm_b[d];
    const float tf = time_first[d];
    const float wd = __expf(time_decay[d]);
    const int seq = blockIdx.x;
    const int bb = seq >> 5, hp = seq & 31;

    float aa = 0.f, bbs = 0.f, pp = -1e30f;
    __syncthreads();

    for (int l = 0; l < 32; ++l) {
        const int fidx = ((l * 4 + bb) * 32 + hp) * 32 + d;
        const float f = feat[fidx];
        // --- LN1 (width-32 shuffle reduce; halves are duplicates) ---
        float s = f;
#pragma unroll
        for (int m = 1; m < 32; m <<= 1) s += __shfl_xor(s, m, 32);
        const float mu = s * (1.f / 32.f);
        const float df = f - mu;
        float vv = df * df;
#pragma unroll
        for (int m = 1; m < 32; m <<= 1) vv += __shfl_xor(vv, m, 32);
        const float xn = df * rsqrtf(vv * (1.f / 32.f) + 1e-5f) * gt + bt;
        if (t < 32) xn_s[d] = xn;
        __syncthreads();
        // --- r, k, v matvecs ---
        float racc = 0.f, kacc = 0.f, vacc = 0.f;
        const float4* xs4 = (const float4*)xn_s;
#pragma unroll
        for (int jq = 0; jq < 8; ++jq) {
            const float4 xj = xs4[jq];
            const int j0 = jq * 4;
            const float* wr = &wT_r[j0 * 33 + d];
            racc += xj.x * wr[0] + xj.y * wr[33] + xj.z * wr[66] + xj.w * wr[99];
            const float* wk = &wT_k[j0 * 33 + d];
            kacc += xj.x * wk[0] + xj.y * wk[33] + xj.z * wk[66] + xj.w * wk[99];
            const float* wv = &wT_v[j0 * 33 + d];
            vacc += xj.x * wv[0] + xj.y * wv[33] + xj.z * wv[66] + xj.w * wv[99];
        }
        const float r = sigf(racc);
        const float k = kacc, v = vacc;
        // --- WKV ---
        const float ww = tf + k;
        const float p = fmaxf(pp, ww);
        const float e1 = __expf(pp - p), e2 = __expf(ww - p);
        const float wkv = (e1 * aa + e2 * v) / fmaxf(e1 * bbs + e2, 1e-8f);
        const float ww2 = pp - wd;
        const float p2 = fmaxf(ww2, k);
        const float e1b = __expf(ww2 - p2), e2b = __expf(k - p2);
        aa = e1b * aa + e2b * v;
        bbs = e1b * bbs + e2b;
        pp = p2;
        if (t < 32) wkv_s[d] = wkv;
        __syncthreads();
        // --- output projection ---
        float oacc = 0.f;
        const float4* wk4 = (const float4*)wkv_s;
#pragma unroll
        for (int jq = 0; jq < 8; ++jq) {
            const float4 xj = wk4[jq];
            const int j0 = jq * 4;
            const float* wo = &wT_o[j0 * 33 + d];
            oacc += xj.x * wo[0] + xj.y * wo[33] + xj.z * wo[66] + xj.w * wo[99];
        }
        const float y = f + r * oacc;
        // --- LN2 ---
        float s2 = y;
#pragma unroll
        for (int m = 1; m < 32; m <<= 1) s2 += __shfl_xor(s2, m, 32);
        const float mu2 = s2 * (1.f / 32.f);
        const float df2 = y - mu2;
        float vv2 = df2 * df2;
#pragma unroll
        for (int m = 1; m < 32; m <<= 1) vv2 += __shfl_xor(vv2, m, 32);
        const float xn2 = df2 * rsqrtf(vv2 * (1.f / 32.f) + 1e-5f) * gc + bc;
        if (t < 32) xn2_s[d] = xn2;
        __syncthreads();
        // --- channel-mix: kk (64 lanes, e = t), cm_r (duplicated halves) ---
        float ck = 0.f, cracc = 0.f;
        const float4* x24 = (const float4*)xn2_s;
#pragma unroll
        for (int jq = 0; jq < 8; ++jq) {
            const float4 xj = x24[jq];
            const int j0 = jq * 4;
            ck += xj.x * wT_ck[(j0 + 0) * 65 + t] + xj.y * wT_ck[(j0 + 1) * 65 + t]
                + xj.z * wT_ck[(j0 + 2) * 65 + t] + xj.w * wT_ck[(j0 + 3) * 65 + t];
            const float* wc = &wT_cr[j0 * 33 + d];
            cracc += xj.x * wc[0] + xj.y * wc[33] + xj.z * wc[66] + xj.w * wc[99];
        }
        float kkv = fmaxf(ck, 0.f);
        kkv *= kkv;
        kk_s[t] = kkv;
        __syncthreads();
        // --- cm_v: dot over 64, split across halves ---
        float cvacc = 0.f;
        const float4* kk4 = (const float4*)&kk_s[half * 32];
#pragma unroll
        for (int jq = 0; jq < 8; ++jq) {
            const float4 xj = kk4[jq];
            const int j0 = half * 32 + jq * 4;
            const float* wv2 = &wT_cv[j0 * 33 + d];
            cvacc += xj.x * wv2[0] + xj.y * wv2[33] + xj.z * wv2[66] + xj.w * wv2[99];
        }
        cvacc += __shfl_xor(cvacc, 32);
        const float y2 = y + sigf(cracc) * cvacc;
        if (t < 32) feats_out[fidx] = y2;
        __syncthreads();
    }
}

// ---------------------------------------------------------------------------
// Kernel C: mask + merge. grid 4096 blocks over (b,l,hp), 256 threads.
// mask = sigmoid(gate + row[h] + col[w]) is separable: compute 129 dots once,
// then stream a/b and write merged. Per-block partial sums -> d_ws.
// ---------------------------------------------------------------------------
__global__ __launch_bounds__(256) void k_merge(
    const float* __restrict__ x, const float* __restrict__ feats,
    const float* __restrict__ gate_w, const float* __restrict__ gate_b,
    const float* __restrict__ row_w, const float* __restrict__ row_b,
    const float* __restrict__ col_w, const float* __restrict__ col_b,
    float* __restrict__ out, float* __restrict__ gpart, float* __restrict__ mpart)
{
    __shared__ float fs[32];
    __shared__ float row_s[64], col_s[64];
    __shared__ float gate_sh;
    __shared__ float red[4];
    const int bid = blockIdx.x;
    const int hp = bid & 31, l = (bid >> 5) & 31, bb = bid >> 10;
    const int t = threadIdx.x;

    if (t < 32) fs[t] = feats[((l * 4 + bb) * 32 + hp) * 32 + t];
    __syncthreads();
    if (t < 64) {
        float acc = row_b[t];
#pragma unroll
        for (int d2 = 0; d2 < 32; ++d2) acc += fs[d2] * row_w[t * 32 + d2];
        row_s[t] = acc;
    } else if (t < 128) {
        const int w = t - 64;
        float acc = col_b[w];
#pragma unroll
        for (int d2 = 0; d2 < 32; ++d2) acc += fs[d2] * col_w[w * 32 + d2];
        col_s[w] = acc;
    } else if (t == 128) {
        float acc = gate_b[0];
#pragma unroll
        for (int d2 = 0; d2 < 32; ++d2) acc += fs[d2] * gate_w[d2];
        gate_sh = acc;
    }
    __syncthreads();
    const float gate = gate_sh;
    const float4* pa = (const float4*)(x + (size_t)(bb * 2048 + l * 32 + hp) * 4096);
    const float4* pb = (const float4*)(x + (size_t)(bb * 2048 + 1024 + l * 32 + hp) * 4096);
    float4* po = (float4*)(out + (size_t)(bb * 1024 + l * 32 + hp) * 4096);

    float msum = 0.f;
#pragma unroll
    for (int it = 0; it < 4; ++it) {
        const int i = t + it * 256;
        const float4 a4 = pa[i];
        const float4 b4 = pb[i];
        const int h = i >> 4, w0 = (i & 15) * 4;
        const float gr = gate + row_s[h];
        const float m0 = sigf(gr + col_s[w0 + 0]);
        const float m1 = sigf(gr + col_s[w0 + 1]);
        const float m2 = sigf(gr + col_s[w0 + 2]);
        const float m3 = sigf(gr + col_s[w0 + 3]);
        float4 o;
        o.x = b4.x + m0 * (a4.x - b4.x);
        o.y = b4.y + m1 * (a4.y - b4.y);
        o.z = b4.z + m2 * (a4.z - b4.z);
        o.w = b4.w + m3 * (a4.w - b4.w);
        po[i] = o;
        msum += m0 + m1 + m2 + m3;
    }
#pragma unroll
    for (int m = 1; m < 64; m <<= 1) msum += __shfl_xor(msum, m);
    if ((t & 63) == 0) red[t >> 6] = msum;
    __syncthreads();
    if (t == 0) {
        mpart[bid] = red[0] + red[1] + red[2] + red[3];
        gpart[bid] = sigf(gate);
    }
}

// ---------------------------------------------------------------------------
// Kernel D: reduce the 4096 per-block partials into the two scalar outputs.
// ---------------------------------------------------------------------------
__global__ __launch_bounds__(256) void k_final(
    const float* __restrict__ gpart, const float* __restrict__ mpart,
    float* __restrict__ out)
{
    __shared__ float rg[4], rm[4];
    const int t = threadIdx.x;
    float gs = 0.f, ms = 0.f;
    for (int i = t; i < 4096; i += 256) { gs += gpart[i]; ms += mpart[i]; }
#pragma unroll
    for (int m = 1; m < 64; m <<= 1) { gs += __shfl_xor(gs, m); ms += __shfl_xor(ms, m); }
    if ((t & 63) == 0) { rg[t >> 6] = gs; rm[t >> 6] = ms; }
    __syncthreads();
    if (t == 0) {
        out[16777216] = (rg[0] + rg[1] + rg[2] + rg[3]) * (1.f / 4096.f);
        out[16777217] = (rm[0] + rm[1] + rm[2] + rm[3]) * (1.f / 16777216.f);
    }
}

extern "C" void kernel_launch(void* const* d_in, const int* in_sizes, int n_in,
                              void* d_out, int out_size, void* d_ws, size_t ws_size,
                              hipStream_t stream) {
    const float* x          = (const float*)d_in[0];
    const float* in_proj_w  = (const float*)d_in[1];
    const float* in_proj_b  = (const float*)d_in[2];
    const float* layer_emb  = (const float*)d_in[3];
    const float* time_decay = (const float*)d_in[4];
    const float* time_first = (const float*)d_in[5];
    const float* ln_tm_g    = (const float*)d_in[6];
    const float* ln_tm_b    = (const float*)d_in[7];
    const float* tm_r       = (const float*)d_in[8];
    const float* tm_k       = (const float*)d_in[9];
    const float* tm_v       = (const float*)d_in[10];
    const float* tm_out     = (const float*)d_in[11];
    const float* ln_cm_g    = (const float*)d_in[12];
    const float* ln_cm_b    = (const float*)d_in[13];
    const float* cm_k       = (const float*)d_in[14];
    const float* cm_v       = (const float*)d_in[15];
    const float* cm_r       = (const float*)d_in[16];
    const float* gate_w     = (const float*)d_in[17];
    const float* gate_b     = (const float*)d_in[18];
    const float* row_w      = (const float*)d_in[19];
    const float* row_b      = (const float*)d_in[20];
    const float* col_w      = (const float*)d_in[21];
    const float* col_b      = (const float*)d_in[22];
    float* out = (float*)d_out;

    float* wsf   = (float*)d_ws;
    float* feat  = wsf;            // 131072 floats: [l][b][hp][d]
    float* fy    = wsf + 131072;   // 131072 floats: scan output
    float* gpart = wsf + 262144;   // 4096
    float* mpart = wsf + 266240;   // 4096

    k_stats<<<dim3(4096), dim3(256), 0, stream>>>(x, in_proj_w, in_proj_b, layer_emb, feat);
    k_scan<<<dim3(128), dim3(64), 0, stream>>>(feat, time_decay, time_first,
                                               ln_tm_g, ln_tm_b, tm_r, tm_k, tm_v, tm_out,
                                               ln_cm_g, ln_cm_b, cm_k, cm_v, cm_r, fy);
    k_merge<<<dim3(4096), dim3(256), 0, stream>>>(x, fy, gate_w, gate_b,
                                                  row_w, row_b, col_w, col_b,
                                                  out, gpart, mpart);
    k_final<<<dim3(1), dim3(256), 0, stream>>>(gpart, mpart, out);
}

// Round 2
// 336.463 us; speedup vs baseline: 1.1101x; 1.1101x over previous
//
#include <hip/hip_runtime.h>
#include <math.h>

// Problem constants: B=4, L=32, HP=32, H=64, W=64, D=32, DFFN=64
// x: (4, 2048, 64, 64) fp32.  a = x[:, :1024], b = x[:, 1024:]
// out: mixed (4*1024*64*64 floats) + sigmoid(gate).mean() + mask.mean()

__device__ __forceinline__ float sigf(float v) { return 1.0f / (1.0f + __expf(-v)); }

// wave-wide broadcast from lane l (compile-time-constant l) via v_readlane
__device__ __forceinline__ float bl(float v, int l) {
    return __int_as_float(__builtin_amdgcn_readlane(__float_as_int(v), l));
}

// ---------------------------------------------------------------------------
// Kernel A: per-(b,l,hp) stats over 4096 elements of a and b, then in_proj.
// grid 4096 blocks, 256 threads. One full read of x (134 MB) -> HBM-bound.
// ---------------------------------------------------------------------------
__global__ __launch_bounds__(256) void k_stats(
    const float* __restrict__ x, const float* __restrict__ in_proj_w,
    const float* __restrict__ in_proj_b, const float* __restrict__ layer_emb,
    float* __restrict__ feat)
{
    __shared__ float red[4][9];
    __shared__ float tot[9];
    const int bid = blockIdx.x;
    const int hp = bid & 31, l = (bid >> 5) & 31, bb = bid >> 10;
    const float4* pa = (const float4*)(x + (size_t)(bb * 2048 + l * 32 + hp) * 4096);
    const float4* pb = (const float4*)(x + (size_t)(bb * 2048 + 1024 + l * 32 + hp) * 4096);
    const int t = threadIdx.x;

    float sa = 0.f, saa = 0.f, sb = 0.f, sbb = 0.f, sab = 0.f;
    float mna = 3.4e38f, mxa = -3.4e38f, mnb = 3.4e38f, mxb = -3.4e38f;
#pragma unroll
    for (int it = 0; it < 4; ++it) {
        float4 a4 = pa[t + it * 256];
        float4 b4 = pb[t + it * 256];
        sa  += a4.x + a4.y + a4.z + a4.w;
        sb  += b4.x + b4.y + b4.z + b4.w;
        saa += a4.x * a4.x + a4.y * a4.y + a4.z * a4.z + a4.w * a4.w;
        sbb += b4.x * b4.x + b4.y * b4.y + b4.z * b4.z + b4.w * b4.w;
        sab += a4.x * b4.x + a4.y * b4.y + a4.z * b4.z + a4.w * b4.w;
        mna = fminf(mna, fminf(fminf(a4.x, a4.y), fminf(a4.z, a4.w)));
        mxa = fmaxf(mxa, fmaxf(fmaxf(a4.x, a4.y), fmaxf(a4.z, a4.w)));
        mnb = fminf(mnb, fminf(fminf(b4.x, b4.y), fminf(b4.z, b4.w)));
        mxb = fmaxf(mxb, fmaxf(fmaxf(b4.x, b4.y), fmaxf(b4.z, b4.w)));
    }
#pragma unroll
    for (int m = 1; m < 64; m <<= 1) {
        sa  += __shfl_xor(sa, m);
        saa += __shfl_xor(saa, m);
        sb  += __shfl_xor(sb, m);
        sbb += __shfl_xor(sbb, m);
        sab += __shfl_xor(sab, m);
        mna = fminf(mna, __shfl_xor(mna, m));
        mxa = fmaxf(mxa, __shfl_xor(mxa, m));
        mnb = fminf(mnb, __shfl_xor(mnb, m));
        mxb = fmaxf(mxb, __shfl_xor(mxb, m));
    }
    const int lane = t & 63, wv = t >> 6;
    if (lane == 0) {
        red[wv][0] = sa;  red[wv][1] = saa; red[wv][2] = sb;  red[wv][3] = sbb;
        red[wv][4] = sab; red[wv][5] = mna; red[wv][6] = mxa; red[wv][7] = mnb;
        red[wv][8] = mxb;
    }
    __syncthreads();
    if (t == 0) {
#pragma unroll
        for (int q = 0; q < 5; ++q) tot[q] = red[0][q] + red[1][q] + red[2][q] + red[3][q];
        tot[5] = fminf(fminf(red[0][5], red[1][5]), fminf(red[2][5], red[3][5]));
        tot[6] = fmaxf(fmaxf(red[0][6], red[1][6]), fmaxf(red[2][6], red[3][6]));
        tot[7] = fminf(fminf(red[0][7], red[1][7]), fminf(red[2][7], red[3][7]));
        tot[8] = fmaxf(fmaxf(red[0][8], red[1][8]), fmaxf(red[2][8], red[3][8]));
    }
    __syncthreads();
    if (t < 32) {
        const float SA = tot[0], SAA = tot[1], SB = tot[2], SBB = tot[3], SAB = tot[4];
        const float inv_n = 1.f / 4096.f, inv_nm1 = 1.f / 4095.f;
        float st[12];
        st[0] = SA * inv_n;
        st[1] = sqrtf(fmaxf(SAA - SA * SA * inv_n, 0.f) * inv_nm1);
        st[2] = tot[5]; st[3] = tot[6];
        st[4] = SB * inv_n;
        st[5] = sqrtf(fmaxf(SBB - SB * SB * inv_n, 0.f) * inv_nm1);
        st[6] = tot[7]; st[7] = tot[8];
        const float SD = SA - SB, SDD = SAA - 2.f * SAB + SBB;
        st[8]  = SD * inv_n;
        st[9]  = sqrtf(fmaxf(SDD - SD * SD * inv_n, 0.f) * inv_nm1);
        st[10] = sqrtf(fmaxf(SDD, 0.f));
        const float na = fmaxf(sqrtf(SAA), 1e-8f), nb2 = fmaxf(sqrtf(SBB), 1e-8f);
        st[11] = SAB / (na * nb2);
        float acc = in_proj_b[t] + layer_emb[l * 32 + t];
#pragma unroll
        for (int s2 = 0; s2 < 12; ++s2) acc += st[s2] * in_proj_w[t * 12 + s2];
        // feat layout: [l][b][hp][d]
        feat[((l * 4 + bb) * 32 + hp) * 32 + t] = acc;
    }
}

// ---------------------------------------------------------------------------
// Kernel B: the RWKV scan. 128 blocks (one per (b,hp) sequence), 64 threads
// (single wave). ALL weights live in VGPRs (lane d holds row d of each
// matrix); every matvec is readlane-broadcast + FMA. Zero LDS, zero
// __syncthreads — all cross-lane traffic is v_readlane / shuffle trees.
// VGPR budget: 5*32 + 32 + 64 = 256 weight regs + ~40 working; 1 wave/SIMD
// is all we can have anyway (128 waves on 256 CUs).
// ---------------------------------------------------------------------------
__global__ __launch_bounds__(64, 1) void k_scan(
    const float* __restrict__ feat,
    const float* __restrict__ time_decay, const float* __restrict__ time_first,
    const float* __restrict__ ln_tm_g, const float* __restrict__ ln_tm_b,
    const float* __restrict__ tm_r, const float* __restrict__ tm_k,
    const float* __restrict__ tm_v, const float* __restrict__ tm_out,
    const float* __restrict__ ln_cm_g, const float* __restrict__ ln_cm_b,
    const float* __restrict__ cm_k, const float* __restrict__ cm_v,
    const float* __restrict__ cm_r, float* __restrict__ feats_out)
{
    const int t = threadIdx.x;
    const int d = t & 31;

    // ---- weights into registers ----
    float w_r[32], w_k[32], w_v[32], w_o[32], w_cr[32], w_ck[32], w_cv[64];
    {
        const float4* pr = (const float4*)(tm_r  + d * 32);
        const float4* pk = (const float4*)(tm_k  + d * 32);
        const float4* pv = (const float4*)(tm_v  + d * 32);
        const float4* po = (const float4*)(tm_out + d * 32);
        const float4* pc = (const float4*)(cm_r  + d * 32);
        const float4* pq = (const float4*)(cm_k  + t * 32);   // lane t: row t of cm_k (64 rows)
        const float4* pw = (const float4*)(cm_v  + d * 64);   // lane: row d of cm_v (64 wide)
#pragma unroll
        for (int jq = 0; jq < 8; ++jq) {
            float4 v;
            v = pr[jq]; w_r[4*jq] = v.x; w_r[4*jq+1] = v.y; w_r[4*jq+2] = v.z; w_r[4*jq+3] = v.w;
            v = pk[jq]; w_k[4*jq] = v.x; w_k[4*jq+1] = v.y; w_k[4*jq+2] = v.z; w_k[4*jq+3] = v.w;
            v = pv[jq]; w_v[4*jq] = v.x; w_v[4*jq+1] = v.y; w_v[4*jq+2] = v.z; w_v[4*jq+3] = v.w;
            v = po[jq]; w_o[4*jq] = v.x; w_o[4*jq+1] = v.y; w_o[4*jq+2] = v.z; w_o[4*jq+3] = v.w;
            v = pc[jq]; w_cr[4*jq] = v.x; w_cr[4*jq+1] = v.y; w_cr[4*jq+2] = v.z; w_cr[4*jq+3] = v.w;
            v = pq[jq]; w_ck[4*jq] = v.x; w_ck[4*jq+1] = v.y; w_ck[4*jq+2] = v.z; w_ck[4*jq+3] = v.w;
        }
#pragma unroll
        for (int jq = 0; jq < 16; ++jq) {
            float4 v = pw[jq];
            w_cv[4*jq] = v.x; w_cv[4*jq+1] = v.y; w_cv[4*jq+2] = v.z; w_cv[4*jq+3] = v.w;
        }
    }
    const float gt = ln_tm_g[d], bt = ln_tm_b[d];
    const float gc = ln_cm_g[d], bc = ln_cm_b[d];
    const float tf = time_first[d];
    const float wd = __expf(time_decay[d]);
    const int seq = blockIdx.x;
    const int bb = seq >> 5, hp = seq & 31;
    const int base = (bb * 32 + hp) * 32 + d;   // + l*4096

    float aa = 0.f, bbs = 0.f, pp = -1e30f;
    float f = feat[base];                        // layer 0 input

    for (int l = 0; l < 32; ++l) {
        float fnext = 0.f;
        if (l < 31) fnext = feat[base + (l + 1) * 4096];   // prefetch next layer
        // --- LN1: fused mean / mean-of-squares tree (width 32) ---
        float s = f, q = f * f;
#pragma unroll
        for (int m = 1; m < 32; m <<= 1) { s += __shfl_xor(s, m, 32); q += __shfl_xor(q, m, 32); }
        const float mu = s * (1.f / 32.f);
        const float var = fmaxf(q * (1.f / 32.f) - mu * mu, 0.f);
        const float xn = (f - mu) * rsqrtf(var + 1e-5f) * gt + bt;
        // --- r, k, v matvecs via readlane broadcast ---
        float racc = 0.f, kacc = 0.f, vacc = 0.f;
#pragma unroll
        for (int j = 0; j < 32; ++j) {
            const float xj = bl(xn, j);
            racc += xj * w_r[j];
            kacc += xj * w_k[j];
            vacc += xj * w_v[j];
        }
        const float r = sigf(racc);
        const float k = kacc, v = vacc;
        // --- WKV ---
        const float ww = tf + k;
        const float p = fmaxf(pp, ww);
        const float e1 = __expf(pp - p), e2 = __expf(ww - p);
        const float wkv = (e1 * aa + e2 * v) / fmaxf(e1 * bbs + e2, 1e-8f);
        const float ww2 = pp - wd;
        const float p2 = fmaxf(ww2, k);
        const float e1b = __expf(ww2 - p2), e2b = __expf(k - p2);
        aa = e1b * aa + e2b * v;
        bbs = e1b * bbs + e2b;
        pp = p2;
        // --- output projection ---
        float oacc = 0.f;
#pragma unroll
        for (int j = 0; j < 32; ++j) oacc += bl(wkv, j) * w_o[j];
        const float y = f + r * oacc;
        // --- LN2 ---
        float s2 = y, q2 = y * y;
#pragma unroll
        for (int m = 1; m < 32; m <<= 1) { s2 += __shfl_xor(s2, m, 32); q2 += __shfl_xor(q2, m, 32); }
        const float mu2 = s2 * (1.f / 32.f);
        const float var2 = fmaxf(q2 * (1.f / 32.f) - mu2 * mu2, 0.f);
        const float xn2 = (y - mu2) * rsqrtf(var2 + 1e-5f) * gc + bc;
        // --- channel-mix: ck over 64 lanes (lane t = output e), cr over d ---
        float ck = 0.f, cracc = 0.f;
#pragma unroll
        for (int j = 0; j < 32; ++j) {
            const float xj = bl(xn2, j);
            ck    += xj * w_ck[j];
            cracc += xj * w_cr[j];
        }
        float kkv = fmaxf(ck, 0.f);
        kkv *= kkv;                               // kk[t], 64 distinct values
        // --- cm_v: dot over 64 via readlane, two independent chains ---
        float cv0 = 0.f, cv1 = 0.f;
#pragma unroll
        for (int e = 0; e < 64; e += 2) {
            cv0 += bl(kkv, e)     * w_cv[e];
            cv1 += bl(kkv, e + 1) * w_cv[e + 1];
        }
        const float y2 = y + sigf(cracc) * (cv0 + cv1);
        if (t < 32) feats_out[base + l * 4096] = y2;
        f = fnext;
    }
}

// ---------------------------------------------------------------------------
// Kernel C: mask + merge. grid 4096 blocks over (b,l,hp), 256 threads.
// mask = sigmoid(gate + row[h] + col[w]) is separable: compute 129 dots once,
// then stream a/b and write merged. Per-block partial sums -> d_ws.
// ---------------------------------------------------------------------------
__global__ __launch_bounds__(256) void k_merge(
    const float* __restrict__ x, const float* __restrict__ feats,
    const float* __restrict__ gate_w, const float* __restrict__ gate_b,
    const float* __restrict__ row_w, const float* __restrict__ row_b,
    const float* __restrict__ col_w, const float* __restrict__ col_b,
    float* __restrict__ out, float* __restrict__ gpart, float* __restrict__ mpart)
{
    __shared__ float fs[32];
    __shared__ float row_s[64], col_s[64];
    __shared__ float gate_sh;
    __shared__ float red[4];
    const int bid = blockIdx.x;
    const int hp = bid & 31, l = (bid >> 5) & 31, bb = bid >> 10;
    const int t = threadIdx.x;

    if (t < 32) fs[t] = feats[((l * 4 + bb) * 32 + hp) * 32 + t];
    __syncthreads();
    if (t < 64) {
        float acc = row_b[t];
#pragma unroll
        for (int d2 = 0; d2 < 32; ++d2) acc += fs[d2] * row_w[t * 32 + d2];
        row_s[t] = acc;
    } else if (t < 128) {
        const int w = t - 64;
        float acc = col_b[w];
#pragma unroll
        for (int d2 = 0; d2 < 32; ++d2) acc += fs[d2] * col_w[w * 32 + d2];
        col_s[w] = acc;
    } else if (t == 128) {
        float acc = gate_b[0];
#pragma unroll
        for (int d2 = 0; d2 < 32; ++d2) acc += fs[d2] * gate_w[d2];
        gate_sh = acc;
    }
    __syncthreads();
    const float gate = gate_sh;
    const float4* pa = (const float4*)(x + (size_t)(bb * 2048 + l * 32 + hp) * 4096);
    const float4* pb = (const float4*)(x + (size_t)(bb * 2048 + 1024 + l * 32 + hp) * 4096);
    float4* po = (float4*)(out + (size_t)(bb * 1024 + l * 32 + hp) * 4096);

    float msum = 0.f;
#pragma unroll
    for (int it = 0; it < 4; ++it) {
        const int i = t + it * 256;
        const float4 a4 = pa[i];
        const float4 b4 = pb[i];
        const int h = i >> 4, w0 = (i & 15) * 4;
        const float gr = gate + row_s[h];
        const float m0 = sigf(gr + col_s[w0 + 0]);
        const float m1 = sigf(gr + col_s[w0 + 1]);
        const float m2 = sigf(gr + col_s[w0 + 2]);
        const float m3 = sigf(gr + col_s[w0 + 3]);
        float4 o;
        o.x = b4.x + m0 * (a4.x - b4.x);
        o.y = b4.y + m1 * (a4.y - b4.y);
        o.z = b4.z + m2 * (a4.z - b4.z);
        o.w = b4.w + m3 * (a4.w - b4.w);
        po[i] = o;
        msum += m0 + m1 + m2 + m3;
    }
#pragma unroll
    for (int m = 1; m < 64; m <<= 1) msum += __shfl_xor(msum, m);
    if ((t & 63) == 0) red[t >> 6] = msum;
    __syncthreads();
    if (t == 0) {
        mpart[bid] = red[0] + red[1] + red[2] + red[3];
        gpart[bid] = sigf(gate);
    }
}

// ---------------------------------------------------------------------------
// Kernel D: reduce the 4096 per-block partials into the two scalar outputs.
// ---------------------------------------------------------------------------
__global__ __launch_bounds__(256) void k_final(
    const float* __restrict__ gpart, const float* __restrict__ mpart,
    float* __restrict__ out)
{
    __shared__ float rg[4], rm[4];
    const int t = threadIdx.x;
    float gs = 0.f, ms = 0.f;
    for (int i = t; i < 4096; i += 256) { gs += gpart[i]; ms += mpart[i]; }
#pragma unroll
    for (int m = 1; m < 64; m <<= 1) { gs += __shfl_xor(gs, m); ms += __shfl_xor(ms, m); }
    if ((t & 63) == 0) { rg[t >> 6] = gs; rm[t >> 6] = ms; }
    __syncthreads();
    if (t == 0) {
        out[16777216] = (rg[0] + rg[1] + rg[2] + rg[3]) * (1.f / 4096.f);
        out[16777217] = (rm[0] + rm[1] + rm[2] + rm[3]) * (1.f / 16777216.f);
    }
}

extern "C" void kernel_launch(void* const* d_in, const int* in_sizes, int n_in,
                              void* d_out, int out_size, void* d_ws, size_t ws_size,
                              hipStream_t stream) {
    const float* x          = (const float*)d_in[0];
    const float* in_proj_w  = (const float*)d_in[1];
    const float* in_proj_b  = (const float*)d_in[2];
    const float* layer_emb  = (const float*)d_in[3];
    const float* time_decay = (const float*)d_in[4];
    const float* time_first = (const float*)d_in[5];
    const float* ln_tm_g    = (const float*)d_in[6];
    const float* ln_tm_b    = (const float*)d_in[7];
    const float* tm_r       = (const float*)d_in[8];
    const float* tm_k       = (const float*)d_in[9];
    const float* tm_v       = (const float*)d_in[10];
    const float* tm_out     = (const float*)d_in[11];
    const float* ln_cm_g    = (const float*)d_in[12];
    const float* ln_cm_b    = (const float*)d_in[13];
    const float* cm_k       = (const float*)d_in[14];
    const float* cm_v       = (const float*)d_in[15];
    const float* cm_r       = (const float*)d_in[16];
    const float* gate_w     = (const float*)d_in[17];
    const float* gate_b     = (const float*)d_in[18];
    const float* row_w      = (const float*)d_in[19];
    const float* row_b      = (const float*)d_in[20];
    const float* col_w      = (const float*)d_in[21];
    const float* col_b      = (const float*)d_in[22];
    float* out = (float*)d_out;

    float* wsf   = (float*)d_ws;
    float* feat  = wsf;            // 131072 floats: [l][b][hp][d]
    float* fy    = wsf + 131072;   // 131072 floats: scan output
    float* gpart = wsf + 262144;   // 4096
    float* mpart = wsf + 266240;   // 4096

    k_stats<<<dim3(4096), dim3(256), 0, stream>>>(x, in_proj_w, in_proj_b, layer_emb, feat);
    k_scan<<<dim3(128), dim3(64), 0, stream>>>(feat, time_decay, time_first,
                                               ln_tm_g, ln_tm_b, tm_r, tm_k, tm_v, tm_out,
                                               ln_cm_g, ln_cm_b, cm_k, cm_v, cm_r, fy);
    k_merge<<<dim3(4096), dim3(256), 0, stream>>>(x, fy, gate_w, gate_b,
                                                  row_w, row_b, col_w, col_b,
                                                  out, gpart, mpart);
    k_final<<<dim3(1), dim3(256), 0, stream>>>(gpart, mpart, out);
}